// Round 1
// baseline (299.461 us; speedup 1.0000x reference)
//
#include <hip/hip_runtime.h>

// Problem: B=256, N=8192, K=16, fp32.
// out[b,n,k] = min(y[n], 0.5*(y[n-1]+y[n+1])) - param   (interior n)
//            = y[n] - param                              (n==0 or n==N-1)
// where y = x + param. Pure memory-bound 3-point stencil along N.

#define B_    256
#define N_    8192
#define K_    16
#define TILE  64          // n-rows per block
#define KQ    4           // K/4 float4 columns per row
#define NTILES (N_ / TILE) // 128

__global__ __launch_bounds__(256)
void convex_kernel(const float4* __restrict__ x4,
                   const float4* __restrict__ p4,
                   float4* __restrict__ o4)
{
    // y-tile with 1-row halo on each side: 66 rows x 4 float4 = 4224 B LDS
    __shared__ float4 ysh[TILE + 2][KQ];

    const int tid = threadIdx.x;
    const int row = tid >> 2;     // 0..63 : n-row within tile
    const int col = tid & 3;      // 0..3  : float4 column within K
    const int blk = blockIdx.x;
    const int t   = blk & (NTILES - 1);  // tile index along N
    const int b   = blk >> 7;            // batch (NTILES == 128)
    const int n0  = t * TILE;

    const long base = ((long)b * N_ + n0) * KQ;   // float4 index of tile origin
    const long idx  = base + (long)row * KQ + col;

    // Main load: each element of x/param read exactly once.
    float4 xv = x4[idx];
    float4 pv = p4[idx];
    float4 yv = make_float4(xv.x + pv.x, xv.y + pv.y, xv.z + pv.z, xv.w + pv.w);
    ysh[row + 1][col] = yv;

    // Halo rows: n0-1 (lanes 0..3) and n0+TILE (lanes 4..7), guarded at the
    // array ends (those values are never consumed there: boundary rows take
    // the y-param path).
    if (tid < 8) {
        const int c = tid & 3;
        float4 h = make_float4(0.f, 0.f, 0.f, 0.f);
        if (tid < 4) {
            if (n0 > 0) {
                float4 hx = x4[base - KQ + c];
                float4 hp = p4[base - KQ + c];
                h = make_float4(hx.x + hp.x, hx.y + hp.y, hx.z + hp.z, hx.w + hp.w);
            }
            ysh[0][c] = h;
        } else {
            if (n0 + TILE < N_) {
                float4 hx = x4[base + (long)TILE * KQ + c];
                float4 hp = p4[base + (long)TILE * KQ + c];
                h = make_float4(hx.x + hp.x, hx.y + hp.y, hx.z + hp.z, hx.w + hp.w);
            }
            ysh[TILE + 1][c] = h;
        }
    }
    __syncthreads();

    const int n = n0 + row;
    float4 r;
    if (n == 0 || n == N_ - 1) {
        // Dy padded to 0 at the ends -> out = y - param
        r = make_float4(yv.x - pv.x, yv.y - pv.y, yv.z - pv.z, yv.w - pv.w);
    } else {
        float4 a = ysh[row][col];      // y[n-1]
        float4 d = ysh[row + 2][col];  // y[n+1]
        float4 m = make_float4(0.5f * (a.x + d.x), 0.5f * (a.y + d.y),
                               0.5f * (a.z + d.z), 0.5f * (a.w + d.w));
        r = make_float4(fminf(yv.x, m.x) - pv.x,
                        fminf(yv.y, m.y) - pv.y,
                        fminf(yv.z, m.z) - pv.z,
                        fminf(yv.w, m.w) - pv.w);
    }
    o4[idx] = r;
}

extern "C" void kernel_launch(void* const* d_in, const int* in_sizes, int n_in,
                              void* d_out, int out_size, void* d_ws, size_t ws_size,
                              hipStream_t stream)
{
    const float4* x = (const float4*)d_in[0];
    const float4* p = (const float4*)d_in[1];
    float4*       o = (float4*)d_out;

    dim3 grid(B_ * NTILES);   // 32768 blocks
    dim3 block(256);
    convex_kernel<<<grid, block, 0, stream>>>(x, p, o);
}